// Round 15
// baseline (192.433 us; speedup 1.0000x reference)
//
#include <hip/hip_runtime.h>

// B=4, L=256, E=128, H=8, D=16, NU=512, NT=256. All I/O fp32.
// 4 dispatches:
//   1. pre_fused : 9 projections (16 rows/block, x via wave-uniform s_load, K transposed)
//                  + CI transpose + fold + gstat zero
//   2. attn      : head-split tasks, XCD-swizzled, fused exp; q via wave-uniform s_load,
//                  p/V vectorized
//   3. epilogue  : y = Cuu@ouu + Cta@ota + Cdu@odu + bias; spread BN stat atomics
//   4. bn_apply  : reduce 16 stat copies, normalize + ReLU

struct PreArgs {
    const float* x[9]; const float* W[9]; const float* bia[9]; float* out[9];
    int Kdim[9]; int transNb[9];
    const float* CIMat; float* cit;
    const float* dim_w; const float* dim_b;
    const float* uu_ow; const float* uu_ob;
    const float* ta_ow; const float* ta_ob;
    const float* du_ow; const float* du_ob;
    float* Cuu; float* Cta; float* Cdu; float* bcomb;
    float* gstat;
};

// tasks: [0,704) proj (16 rows each), [704,1728) CI transpose, [1728,1856) fold
__global__ __launch_bounds__(256) void pre_fused(PreArgs A)
{
    __shared__ __align__(16) float smem[1056];
    int bid = blockIdx.x, tid = threadIdx.x;
    if (bid == 0)
        for (int i = tid; i < 16 * 256; i += 256) A.gstat[i] = 0.f;

    if (bid < 704) {
        // ---- projection: 16 rows per block; x read via wave-uniform scalar loads ----
        int task, mblk;
        if (bid < 448) { task = bid >> 6; mblk = bid & 63; }
        else { int r = bid - 448; task = 7 + (r >> 7); mblk = r & 127; }
        int Kd = A.Kdim[task];
        const float* x = A.x[task];
        int m0 = mblk * 16;
        int e = tid & 127;
        int r0 = __builtin_amdgcn_readfirstlane((tid >> 7) * 8);  // wave-uniform row half
        const float4* w4 = (const float4*)(A.W[task] + (size_t)e * 128);
        float acc[8];
        float bv = A.bia[task][e];
#pragma unroll
        for (int r = 0; r < 8; ++r) acc[r] = bv;
        if (Kd == 128) {
            const float* xbase = x + (size_t)(m0 + r0) * 128;
#pragma unroll 8
            for (int c = 0; c < 32; ++c) {
                float4 w = w4[c];
#pragma unroll
                for (int r = 0; r < 8; ++r) {
                    const float* xr = xbase + r * 128 + c * 4;   // uniform -> s_load
                    acc[r] += w.x * xr[0] + w.y * xr[1] + w.z * xr[2] + w.w * xr[3];
                }
            }
        } else {   // Kd == 126: full unroll so the c==31 tail never loads OOB
            const float* xbase = x + (size_t)(m0 + r0) * 126;
#pragma unroll
            for (int c = 0; c < 32; ++c) {
                float4 w = w4[c];
#pragma unroll
                for (int r = 0; r < 8; ++r) {
                    const float* xr = xbase + r * 126 + c * 4;
                    float s0 = xr[0], s1 = xr[1];
                    float s2 = (c < 31) ? xr[2] : 0.f;
                    float s3 = (c < 31) ? xr[3] : 0.f;
                    acc[r] += w.x * s0 + w.y * s1 + w.z * s2 + w.w * s3;
                }
            }
        }
        int nb = A.transNb[task];
        float* op = A.out[task];
        if (nb == 0) {
#pragma unroll
            for (int r = 0; r < 8; ++r)
                op[(size_t)(m0 + r0 + r) * 128 + e] = acc[r];
        } else {
            int b = m0 / nb, nloc = m0 - b * nb;
            float* o = op + ((size_t)b * 128 + e) * nb + nloc + r0;
            float4 v0 = { acc[0], acc[1], acc[2], acc[3] };
            float4 v1 = { acc[4], acc[5], acc[6], acc[7] };
            *(float4*)o = v0;
            *(float4*)(o + 4) = v1;
        }
    } else if (bid < 1728) {
        // ---- CI transpose ----
        int tb = bid - 704;
        int b = tb >> 8, tt = tb & 255;
        int n0 = (tt >> 4) * 32, c0 = (tt & 15) * 32;
        float (*tile)[33] = (float(*)[33])smem;
        int tx = tid & 31, ty = tid >> 5;
        const float* src = A.CIMat + (size_t)b * 262144;
        float* dst = A.cit + (size_t)b * 262144;
#pragma unroll
        for (int i = ty; i < 32; i += 8)
            tile[i][tx] = src[(size_t)(n0 + i) * 512 + c0 + tx];
        __syncthreads();
#pragma unroll
        for (int i = ty; i < 32; i += 8)
            dst[(size_t)(c0 + i) * 512 + n0 + tx] = tile[tx][i];
    } else {
        // ---- fold out-projections into dim projection ----
        float* ds = smem;
        float* red = smem + 384;
        int e = bid - 1728, k = tid;
        if (k < 128) {
            ds[k]       = A.dim_w[(size_t)e * 384 + k];
            ds[128 + k] = A.dim_w[(size_t)e * 384 + 128 + k];
            ds[256 + k] = A.dim_w[(size_t)e * 384 + 256 + k];
        }
        __syncthreads();
        if (k < 128) {
            float cu = 0.f, ct = 0.f, cd = 0.f;
#pragma unroll 4
            for (int j = 0; j < 128; ++j) {
                cu += ds[j]       * A.uu_ow[(size_t)j * 128 + k];
                ct += ds[128 + j] * A.ta_ow[(size_t)j * 128 + k];
                cd += ds[256 + j] * A.du_ow[(size_t)j * 128 + k];
            }
            A.Cuu[(size_t)e * 128 + k] = cu;
            A.Cta[(size_t)e * 128 + k] = ct;
            A.Cdu[(size_t)e * 128 + k] = cd;
            red[k] = ds[k] * A.uu_ob[k] + ds[128 + k] * A.ta_ob[k] + ds[256 + k] * A.du_ob[k];
        }
        __syncthreads();
        for (int off = 64; off; off >>= 1) {
            if (k < off) red[k] += red[k + off];
            __syncthreads();
        }
        if (k == 0) A.bcomb[e] = A.dim_b[e] + red[0];
    }
}

struct AttnArgs {
    const float* qd; const float* kbaseT; const float* vbase; const float* cit;
    const float* qta; const float* ktaT; const float* vta;
    const float* qdu; const float* kduT; const float* vdu;
    const float* uu_in_w;
    float* ouu; float* ota; float* odu;
};

#define SCP 260   // ta/du sc row pitch
#define SCPU 516  // uu sc row pitch

// 3072 blocks. XCD swizzle: xcd = bid&7 -> b = xcd>>1. t = half*384 + idx:
//   t<256: ta/du (2h x 8r, N=256); t>=256: uu (2h x 2r, N=512)
__global__ __launch_bounds__(256) void attn_kernel(AttnArgs A)
{
    __shared__ __align__(16) float smem[5472];
    int bid = blockIdx.x, tid = threadIdx.x;
    int xcd = bid & 7, idx = bid >> 3;
    int b = xcd >> 1, half = xcd & 1;
    int t = half * 384 + idx;

    if (t < 256) {
        // ================= ta / du: 2 heads x 8 rows, N=256 =================
        int kind = t >> 7;
        int u = t & 127;
        int hg = u >> 5, lt = u & 31;
        int l0 = lt * 8, bl0 = b * 256 + l0;
        const float* q  = kind ? A.qdu  : A.qta;
        const float* kT = kind ? A.kduT : A.ktaT;
        const float* v  = kind ? A.vdu  : A.vta;
        float* o        = kind ? A.odu  : A.ota;
        float* sc    = smem;           // 16 rows x SCP
        float* vpart = smem + 4160;    // 1024
        float* den   = smem + 5184;    // 16
        const float* qrow = q + (size_t)bl0 * 128 + hg * 32;   // uniform base
        {   // scores + fused exp; q via wave-uniform s_load
            int n = tid;
            const float* kp = kT + ((size_t)b * 128 + hg * 32) * 256 + n;
            float acc[8][2];
#pragma unroll
            for (int l = 0; l < 8; ++l) { acc[l][0] = 0.f; acc[l][1] = 0.f; }
#pragma unroll
            for (int d4 = 0; d4 < 8; ++d4) {
                int hl = d4 >> 2;
                float kv0 = kp[(size_t)(d4 * 4)     * 256];
                float kv1 = kp[(size_t)(d4 * 4 + 1) * 256];
                float kv2 = kp[(size_t)(d4 * 4 + 2) * 256];
                float kv3 = kp[(size_t)(d4 * 4 + 3) * 256];
#pragma unroll
                for (int l = 0; l < 8; ++l) {
                    const float* qp = qrow + l * 128 + d4 * 4;   // uniform -> s_load
                    acc[l][hl] += qp[0] * kv0 + qp[1] * kv1 + qp[2] * kv2 + qp[3] * kv3;
                }
            }
#pragma unroll
            for (int hl = 0; hl < 2; ++hl)
#pragma unroll
                for (int l = 0; l < 8; ++l)
                    sc[(hl * 8 + l) * SCP + n] = __expf(acc[l][hl] * 0.25f);
        }
        __syncthreads();
        {   // den: 16 groups x 16 lanes, strided float4 row sums
            int g = tid >> 4, j = tid & 15;
            const float4* row4 = (const float4*)(sc + g * SCP);
            float4 s4 = row4[j];
            float4 b1 = row4[j + 16], b2 = row4[j + 32], b3 = row4[j + 48];
            s4.x += b1.x + b2.x + b3.x; s4.y += b1.y + b2.y + b3.y;
            s4.z += b1.z + b2.z + b3.z; s4.w += b1.w + b2.w + b3.w;
            float s = s4.x + s4.y + s4.z + s4.w;
#pragma unroll
            for (int off = 8; off; off >>= 1) s += __shfl_down(s, off, 16);
            if (j == 0) den[g] = s;
        }
        __syncthreads();
        {   // V pass: p via float4 over n; coalesced float4 V rows
            int col4 = tid & 7, l = (tid >> 3) & 7, nh = tid >> 6;
            const float4* v4 = (const float4*)v + (size_t)b * 256 * 32 + hg * 8 + col4;
            const float4* p4 = (const float4*)(sc + ((col4 >> 2) * 8 + l) * SCP) + nh * 16;
            float4 a4 = { 0.f, 0.f, 0.f, 0.f };
            int n0 = nh * 64;
#pragma unroll 4
            for (int n4 = 0; n4 < 16; ++n4) {
                float4 pv = p4[n4];
                int n = n0 + n4 * 4;
                float4 vv0 = v4[(size_t)n * 32];
                float4 vv1 = v4[(size_t)(n + 1) * 32];
                float4 vv2 = v4[(size_t)(n + 2) * 32];
                float4 vv3 = v4[(size_t)(n + 3) * 32];
                a4.x += pv.x * vv0.x + pv.y * vv1.x + pv.z * vv2.x + pv.w * vv3.x;
                a4.y += pv.x * vv0.y + pv.y * vv1.y + pv.z * vv2.y + pv.w * vv3.y;
                a4.z += pv.x * vv0.z + pv.y * vv1.z + pv.z * vv2.z + pv.w * vv3.z;
                a4.w += pv.x * vv0.w + pv.y * vv1.w + pv.z * vv2.w + pv.w * vv3.w;
            }
            ((float4*)vpart)[nh * 64 + l * 8 + col4] = a4;
        }
        __syncthreads();
        {   // reduce 4 n-chunks + write
            int col = tid & 31, l = tid >> 5;
            int col4 = col >> 2, j = col & 3;
            int base = (l * 8 + col4) * 4 + j;
            float sum = vpart[base] + vpart[256 + base] + vpart[512 + base] + vpart[768 + base];
            o[(size_t)(bl0 + l) * 128 + hg * 32 + col] = sum / den[(col >> 4) * 8 + l];
        }
    } else {
        // ================= uu: 2 heads x 2 rows, N=512, rank-2 ci =================
        int u = t - 256;
        int hg = u >> 7, lt = u & 127;
        int l0 = lt * 2, bl0 = b * 256 + l0;
        float* sc    = smem;           // 4 rows x SCPU = 2064
        float* ci0s  = smem + 2064;    // 1024 [l][n]
        float* ci1s  = smem + 3088;    // 1024
        float* vpart = smem + 4112;    // 1024
        float* qkA   = smem + 5136;    // 4 [hl*2+l]
        float* qkB   = qkA + 4;
        float* den   = qkB + 4;
        float* hs0   = den + 4;
        float* hs1   = hs0 + 4;
        {   // stage ci rows (contiguous) + compute qkA/qkB (4 threads, global reads)
            ((float4*)ci0s)[tid] = ((const float4*)(A.cit + ((size_t)b * 512 + l0) * 512))[tid];
            ((float4*)ci1s)[tid] = ((const float4*)(A.cit + ((size_t)b * 512 + 256 + l0) * 512))[tid];
            if (tid < 4) {
                int hl = tid >> 1, l = tid & 1;
                float a = 0.f, c = 0.f;
#pragma unroll
                for (int d = 0; d < 16; ++d) {
                    float qv = A.qd[(size_t)(bl0 + l) * 128 + hg * 32 + hl * 16 + d];
                    int wr = 128 + hg * 32 + hl * 16 + d;
                    a += qv * A.uu_in_w[(size_t)wr * 128 + 126];
                    c += qv * A.uu_in_w[(size_t)wr * 128 + 127];
                }
                qkA[tid] = a; qkB[tid] = c;
            }
        }
        __syncthreads();
        const float* qrow = A.qd + (size_t)bl0 * 128 + hg * 32;   // uniform base
        {   // scores + fused exp; q via wave-uniform s_load
            const float* kp = A.kbaseT + ((size_t)b * 128 + hg * 32) * 512 + tid;
            float acc[2][2][2];    // [chunk][l][hl]
#pragma unroll
            for (int r = 0; r < 2; ++r)
#pragma unroll
                for (int l = 0; l < 2; ++l) { acc[r][l][0] = 0.f; acc[r][l][1] = 0.f; }
#pragma unroll
            for (int d4 = 0; d4 < 8; ++d4) {
                int hl = d4 >> 2;
                float kva[4], kvb[4];
#pragma unroll
                for (int j = 0; j < 4; ++j) {
                    kva[j] = kp[(size_t)(d4 * 4 + j) * 512];
                    kvb[j] = kp[(size_t)(d4 * 4 + j) * 512 + 256];
                }
#pragma unroll
                for (int l = 0; l < 2; ++l) {
                    const float* qp = qrow + l * 128 + d4 * 4;   // uniform -> s_load
                    acc[0][l][hl] += qp[0] * kva[0] + qp[1] * kva[1] + qp[2] * kva[2] + qp[3] * kva[3];
                    acc[1][l][hl] += qp[0] * kvb[0] + qp[1] * kvb[1] + qp[2] * kvb[2] + qp[3] * kvb[3];
                }
            }
#pragma unroll
            for (int r = 0; r < 2; ++r) {
                int n = tid + r * 256;
#pragma unroll
                for (int l = 0; l < 2; ++l) {
                    float c0 = ci0s[l * 512 + n], c1 = ci1s[l * 512 + n];
#pragma unroll
                    for (int hl = 0; hl < 2; ++hl) {
                        int g = hl * 2 + l;
                        sc[g * SCPU + n] =
                            __expf((acc[r][l][hl] + c0 * qkA[g] + c1 * qkB[g]) * 0.25f);
                    }
                }
            }
        }
        __syncthreads();
        {   // den + ci sums: 4 groups x 64 lanes, float4 reads
            int g = tid >> 6, j = tid & 63;
            int l = g & 1;
            const float4* row4 = (const float4*)(sc + g * SCPU);
            const float4* c04 = (const float4*)(ci0s + l * 512);
            const float4* c14 = (const float4*)(ci1s + l * 512);
            float s = 0.f, a0 = 0.f, a1 = 0.f;
#pragma unroll
            for (int k = 0; k < 2; ++k) {
                float4 pv = row4[j + k * 64];
                float4 cv0 = c04[j + k * 64];
                float4 cv1 = c14[j + k * 64];
                s  += pv.x + pv.y + pv.z + pv.w;
                a0 += pv.x * cv0.x + pv.y * cv0.y + pv.z * cv0.z + pv.w * cv0.w;
                a1 += pv.x * cv1.x + pv.y * cv1.y + pv.z * cv1.z + pv.w * cv1.w;
            }
#pragma unroll
            for (int off = 32; off; off >>= 1) {
                s  += __shfl_down(s, off, 64);
                a0 += __shfl_down(a0, off, 64);
                a1 += __shfl_down(a1, off, 64);
            }
            if (j == 0) { den[g] = s; hs0[g] = a0; hs1[g] = a1; }
        }
        __syncthreads();
        {   // V pass: p via float4 over n
            int col4 = tid & 7, l = (tid >> 3) & 1, nh = tid >> 4;
            const float4* v4 = (const float4*)A.vbase + (size_t)b * 512 * 32 + hg * 8 + col4;
            const float4* p4 = (const float4*)(sc + ((col4 >> 2) * 2 + l) * SCPU) + nh * 8;
            float4 a4 = { 0.f, 0.f, 0.f, 0.f };
            int n0 = nh * 32;
#pragma unroll 4
            for (int n4 = 0; n4 < 8; ++n4) {
                float4 pv = p4[n4];
                int n = n0 + n4 * 4;
                float4 vv0 = v4[(size_t)n * 32];
                float4 vv1 = v4[(size_t)(n + 1) * 32];
                float4 vv2 = v4[(size_t)(n + 2) * 32];
                float4 vv3 = v4[(size_t)(n + 3) * 32];
                a4.x += pv.x * vv0.x + pv.y * vv1.x + pv.z * vv2.x + pv.w * vv3.x;
                a4.y += pv.x * vv0.y + pv.y * vv1.y + pv.z * vv2.y + pv.w * vv3.y;
                a4.z += pv.x * vv0.z + pv.y * vv1.z + pv.z * vv2.z + pv.w * vv3.z;
                a4.w += pv.x * vv0.w + pv.y * vv1.w + pv.z * vv2.w + pv.w * vv3.w;
            }
            ((float4*)vpart)[nh * 16 + l * 8 + col4] = a4;
        }
        __syncthreads();
        if (tid < 64) {   // reduce 16 n-chunks + rank-2 V correction + write
            int col = tid & 31, l = tid >> 5;
            int colglob = hg * 32 + col;
            int g = (col >> 4) * 2 + l;
            int base = (l * 8 + (col >> 2)) * 4 + (col & 3);
            float sum = 0.f;
#pragma unroll
            for (int nh = 0; nh < 16; ++nh) sum += vpart[nh * 64 + base];
            float wv126 = A.uu_in_w[(size_t)(256 + colglob) * 128 + 126];
            float wv127 = A.uu_in_w[(size_t)(256 + colglob) * 128 + 127];
            A.ouu[(size_t)(bl0 + l) * 128 + colglob] =
                (sum + hs0[g] * wv126 + hs1[g] * wv127) / den[g];
        }
    }
}

// epilogue: 256 blocks x 4 rows
__global__ __launch_bounds__(256) void epilogue_kernel(
    const float* __restrict__ ouu, const float* __restrict__ ota,
    const float* __restrict__ odu,
    const float* __restrict__ Cuu, const float* __restrict__ Cta,
    const float* __restrict__ Cdu, const float* __restrict__ bcomb,
    float* __restrict__ y, float* __restrict__ gstat)
{
    __shared__ __align__(16) float xs[4 * 384];
    __shared__ float vp[512];
    int m0 = blockIdx.x * 4;
    int tid = threadIdx.x;
    for (int i = tid; i < 1536; i += 256) {
        int r = i / 384, c = i - r * 384;
        float v;
        if (c < 128)      v = ouu[(size_t)(m0 + r) * 128 + c];
        else if (c < 256) v = ota[(size_t)(m0 + r) * 128 + c - 128];
        else              v = odu[(size_t)(m0 + r) * 128 + c - 256];
        xs[i] = v;
    }
    __syncthreads();
    int e = tid & 127, half = tid >> 7;
    const float4* cu4 = (const float4*)(Cuu + (size_t)e * 128);
    const float4* ct4 = (const float4*)(Cta + (size_t)e * 128);
    const float4* cd4 = (const float4*)(Cdu + (size_t)e * 128);
    const float4* xs4 = (const float4*)xs;
    float bc = bcomb[e];
    float acc[2] = { bc, bc };
    int r0 = half * 2;
#pragma unroll 4
    for (int c = 0; c < 32; ++c) {
        float4 a = cu4[c], bb = ct4[c], d = cd4[c];
#pragma unroll
        for (int rr = 0; rr < 2; ++rr) {
            float4 xu = xs4[(r0 + rr) * 96 + c];
            float4 xt = xs4[(r0 + rr) * 96 + 32 + c];
            float4 xd = xs4[(r0 + rr) * 96 + 64 + c];
            acc[rr] += a.x * xu.x + a.y * xu.y + a.z * xu.z + a.w * xu.w
                     + bb.x * xt.x + bb.y * xt.y + bb.z * xt.z + bb.w * xt.w
                     + d.x * xd.x + d.y * xd.y + d.z * xd.z + d.w * xd.w;
        }
    }
#pragma unroll
    for (int rr = 0; rr < 2; ++rr)
        y[(size_t)(m0 + r0 + rr) * 128 + e] = acc[rr];
    vp[tid] = acc[0] + acc[1];
    vp[256 + tid] = acc[0] * acc[0] + acc[1] * acc[1];
    __syncthreads();
    if (tid < 128) {
        float* gs = gstat + (blockIdx.x & 15) * 256;
        atomicAdd(gs + tid, vp[tid] + vp[tid + 128]);
        atomicAdd(gs + 128 + tid, vp[256 + tid] + vp[256 + tid + 128]);
    }
}

__global__ __launch_bounds__(256) void bn_apply(
    const float* __restrict__ y, const float* __restrict__ gstat,
    const float* __restrict__ gamma, const float* __restrict__ beta,
    float* __restrict__ out)
{
    int gid = blockIdx.x * 256 + threadIdx.x;
    int c0 = (gid & 31) * 4;
    float4 v = ((const float4*)y)[gid];
    float r[4] = { v.x, v.y, v.z, v.w };
#pragma unroll
    for (int k = 0; k < 4; ++k) {
        int c = c0 + k;
        float s = 0.f, s2 = 0.f;
#pragma unroll
        for (int cp = 0; cp < 16; ++cp) {
            s  += gstat[cp * 256 + c];
            s2 += gstat[cp * 256 + 128 + c];
        }
        float mean = s * (1.f / 1024.f);
        float var = s2 * (1.f / 1024.f) - mean * mean;
        float inv = rsqrtf(var + 1e-5f);
        r[k] = fmaxf((r[k] - mean) * inv * gamma[c] + beta[c], 0.f);
    }
    float4 ov = { r[0], r[1], r[2], r[3] };
    ((float4*)out)[gid] = ov;
}

extern "C" void kernel_launch(void* const* d_in, const int* in_sizes, int n_in,
                              void* d_out, int out_size, void* d_ws, size_t ws_size,
                              hipStream_t stream)
{
    (void)in_sizes; (void)n_in; (void)out_size; (void)ws_size;
    const float* UUMat    = (const float*)d_in[0];
    const float* DUMat    = (const float*)d_in[1];
    const float* TAMat    = (const float*)d_in[2];
    const float* CIMat    = (const float*)d_in[3];
    const float* uu_in_w  = (const float*)d_in[4];
    const float* uu_in_b  = (const float*)d_in[5];
    const float* uu_out_w = (const float*)d_in[6];
    const float* uu_out_b = (const float*)d_in[7];
    const float* ta_in_w  = (const float*)d_in[8];
    const float* ta_in_b  = (const float*)d_in[9];
    const float* ta_out_w = (const float*)d_in[10];
    const float* ta_out_b = (const float*)d_in[11];
    const float* du_in_w  = (const float*)d_in[12];
    const float* du_in_b  = (const float*)d_in[13];
    const float* du_out_w = (const float*)d_in[14];
    const float* du_out_b = (const float*)d_in[15];
    const float* dim_w    = (const float*)d_in[16];
    const float* dim_b    = (const float*)d_in[17];
    const float* bn_g     = (const float*)d_in[18];
    const float* bn_b     = (const float*)d_in[19];

    const int BL = 1024, BN = 2048;
    float* ws = (float*)d_ws;
    float* gstat  = ws; ws += 16 * 256;
    float* cit    = ws; ws += (size_t)4 * 512 * 512;
    float* qd     = ws; ws += (size_t)BL * 128;
    float* kbaseT = ws; ws += (size_t)BN * 128;   // [b][128][512]
    float* vbase  = ws; ws += (size_t)BN * 128;
    float* qta    = ws; ws += (size_t)BL * 128;
    float* ktaT   = ws; ws += (size_t)BL * 128;   // [b][128][256]
    float* vta    = ws; ws += (size_t)BL * 128;
    float* qdu    = ws; ws += (size_t)BL * 128;
    float* kduT   = ws; ws += (size_t)BL * 128;   // [b][128][256]
    float* vdu    = ws; ws += (size_t)BL * 128;
    float* ouu    = ws; ws += (size_t)BL * 128;
    float* ota    = ws; ws += (size_t)BL * 128;
    float* odu    = ws; ws += (size_t)BL * 128;
    float* yy     = ws; ws += (size_t)BL * 128;
    float* Cuu    = ws; ws += 128 * 128;
    float* Cta    = ws; ws += 128 * 128;
    float* Cdu    = ws; ws += 128 * 128;
    float* bcomb  = ws; ws += 128;

    PreArgs P;
    P.x[0] = DUMat; P.W[0] = uu_in_w;             P.bia[0] = uu_in_b;       P.out[0] = qd;     P.Kdim[0] = 128; P.transNb[0] = 0;
    P.x[1] = DUMat; P.W[1] = ta_in_w;             P.bia[1] = ta_in_b;       P.out[1] = qta;    P.Kdim[1] = 128; P.transNb[1] = 0;
    P.x[2] = TAMat; P.W[2] = ta_in_w + 128 * 128; P.bia[2] = ta_in_b + 128; P.out[2] = ktaT;   P.Kdim[2] = 128; P.transNb[2] = 256;
    P.x[3] = TAMat; P.W[3] = ta_in_w + 256 * 128; P.bia[3] = ta_in_b + 256; P.out[3] = vta;    P.Kdim[3] = 128; P.transNb[3] = 0;
    P.x[4] = DUMat; P.W[4] = du_in_w;             P.bia[4] = du_in_b;       P.out[4] = qdu;    P.Kdim[4] = 128; P.transNb[4] = 0;
    P.x[5] = DUMat; P.W[5] = du_in_w + 128 * 128; P.bia[5] = du_in_b + 128; P.out[5] = kduT;   P.Kdim[5] = 128; P.transNb[5] = 256;
    P.x[6] = DUMat; P.W[6] = du_in_w + 256 * 128; P.bia[6] = du_in_b + 256; P.out[6] = vdu;    P.Kdim[6] = 128; P.transNb[6] = 0;
    P.x[7] = UUMat; P.W[7] = uu_in_w + 128 * 128; P.bia[7] = uu_in_b + 128; P.out[7] = kbaseT; P.Kdim[7] = 126; P.transNb[7] = 512;
    P.x[8] = UUMat; P.W[8] = uu_in_w + 256 * 128; P.bia[8] = uu_in_b + 256; P.out[8] = vbase;  P.Kdim[8] = 126; P.transNb[8] = 0;
    P.CIMat = CIMat; P.cit = cit;
    P.dim_w = dim_w; P.dim_b = dim_b;
    P.uu_ow = uu_out_w; P.uu_ob = uu_out_b;
    P.ta_ow = ta_out_w; P.ta_ob = ta_out_b;
    P.du_ow = du_out_w; P.du_ob = du_out_b;
    P.Cuu = Cuu; P.Cta = Cta; P.Cdu = Cdu; P.bcomb = bcomb;
    P.gstat = gstat;

    AttnArgs T;
    T.qd = qd; T.kbaseT = kbaseT; T.vbase = vbase; T.cit = cit;
    T.qta = qta; T.ktaT = ktaT; T.vta = vta;
    T.qdu = qdu; T.kduT = kduT; T.vdu = vdu;
    T.uu_in_w = uu_in_w;
    T.ouu = ouu; T.ota = ota; T.odu = odu;

    hipLaunchKernelGGL(pre_fused, dim3(1856), dim3(256), 0, stream, P);
    hipLaunchKernelGGL(attn_kernel, dim3(3072), dim3(256), 0, stream, T);
    hipLaunchKernelGGL(epilogue_kernel, dim3(256), dim3(256), 0, stream,
                       ouu, ota, odu, Cuu, Cta, Cdu, bcomb, yy, gstat);
    hipLaunchKernelGGL(bn_apply, dim3(128), dim3(256), 0, stream,
                       yy, gstat, bn_g, bn_b, (float*)d_out);
}

// Round 16
// 162.740 us; speedup vs baseline: 1.1825x; 1.1825x over previous
//
#include <hip/hip_runtime.h>

// B=4, L=256, E=128, H=8, D=16, NU=512, NT=256. All I/O fp32.
// R16 = revert to the R14 structure (best measured: 162.8 us).
// 4 dispatches:
//   1. pre_fused : 9 projections (16 rows/block, LDS x-stage, K transposed) + CI transpose
//                  + fold + gstat zero
//   2. attn      : head-split tasks, XCD-swizzled, fused exp; ALL LDS reads vectorized (b128)
//   3. epilogue  : y = Cuu@ouu + Cta@ota + Cdu@odu + bias; spread BN stat atomics
//   4. bn_apply  : reduce 16 stat copies, normalize + ReLU

struct PreArgs {
    const float* x[9]; const float* W[9]; const float* bia[9]; float* out[9];
    int Kdim[9]; int transNb[9];
    const float* CIMat; float* cit;
    const float* dim_w; const float* dim_b;
    const float* uu_ow; const float* uu_ob;
    const float* ta_ow; const float* ta_ob;
    const float* du_ow; const float* du_ob;
    float* Cuu; float* Cta; float* Cdu; float* bcomb;
    float* gstat;
};

// tasks: [0,704) proj (16 rows each), [704,1728) CI transpose, [1728,1856) fold
__global__ __launch_bounds__(256) void pre_fused(PreArgs A)
{
    __shared__ __align__(16) float smem[2048];
    int bid = blockIdx.x, tid = threadIdx.x;
    if (bid == 0)
        for (int i = tid; i < 16 * 256; i += 256) A.gstat[i] = 0.f;

    if (bid < 704) {
        int task, mblk;
        if (bid < 448) { task = bid >> 6; mblk = bid & 63; }
        else { int r = bid - 448; task = 7 + (r >> 7); mblk = r & 127; }
        int Kd = A.Kdim[task];
        const float* x = A.x[task];
        int m0 = mblk * 16;
        if (Kd == 128) {
            const float4* x4 = (const float4*)(x + (size_t)m0 * 128);
            ((float4*)smem)[tid] = x4[tid];
            ((float4*)smem)[tid + 256] = x4[tid + 256];
        } else {
            for (int i = tid; i < 2048; i += 256) {
                int r = i >> 7, c = i & 127;
                smem[i] = (c < Kd) ? x[(size_t)(m0 + r) * Kd + c] : 0.f;
            }
        }
        __syncthreads();
        int e = tid & 127, half = tid >> 7;
        int r0 = half * 8;
        const float4* w4 = (const float4*)(A.W[task] + (size_t)e * 128);
        const float4* xs4 = (const float4*)smem;
        float acc[8];
        float bv = A.bia[task][e];
#pragma unroll
        for (int r = 0; r < 8; ++r) acc[r] = bv;
#pragma unroll 8
        for (int c = 0; c < 32; ++c) {
            float4 w = w4[c];
#pragma unroll
            for (int r = 0; r < 8; ++r) {
                float4 xv = xs4[(r0 + r) * 32 + c];
                acc[r] += w.x * xv.x + w.y * xv.y + w.z * xv.z + w.w * xv.w;
            }
        }
        int nb = A.transNb[task];
        float* op = A.out[task];
        if (nb == 0) {
#pragma unroll
            for (int r = 0; r < 8; ++r)
                op[(size_t)(m0 + r0 + r) * 128 + e] = acc[r];
        } else {
            int b = m0 / nb, nloc = m0 - b * nb;
            float* o = op + ((size_t)b * 128 + e) * nb + nloc + r0;
            float4 v0 = { acc[0], acc[1], acc[2], acc[3] };
            float4 v1 = { acc[4], acc[5], acc[6], acc[7] };
            *(float4*)o = v0;
            *(float4*)(o + 4) = v1;
        }
    } else if (bid < 1728) {
        int tb = bid - 704;
        int b = tb >> 8, tt = tb & 255;
        int n0 = (tt >> 4) * 32, c0 = (tt & 15) * 32;
        float (*tile)[33] = (float(*)[33])smem;
        int tx = tid & 31, ty = tid >> 5;
        const float* src = A.CIMat + (size_t)b * 262144;
        float* dst = A.cit + (size_t)b * 262144;
#pragma unroll
        for (int i = ty; i < 32; i += 8)
            tile[i][tx] = src[(size_t)(n0 + i) * 512 + c0 + tx];
        __syncthreads();
#pragma unroll
        for (int i = ty; i < 32; i += 8)
            dst[(size_t)(c0 + i) * 512 + n0 + tx] = tile[tx][i];
    } else {
        float* ds = smem;
        float* red = smem + 384;
        int e = bid - 1728, k = tid;
        if (k < 128) {
            ds[k]       = A.dim_w[(size_t)e * 384 + k];
            ds[128 + k] = A.dim_w[(size_t)e * 384 + 128 + k];
            ds[256 + k] = A.dim_w[(size_t)e * 384 + 256 + k];
        }
        __syncthreads();
        if (k < 128) {
            float cu = 0.f, ct = 0.f, cd = 0.f;
#pragma unroll 4
            for (int j = 0; j < 128; ++j) {
                cu += ds[j]       * A.uu_ow[(size_t)j * 128 + k];
                ct += ds[128 + j] * A.ta_ow[(size_t)j * 128 + k];
                cd += ds[256 + j] * A.du_ow[(size_t)j * 128 + k];
            }
            A.Cuu[(size_t)e * 128 + k] = cu;
            A.Cta[(size_t)e * 128 + k] = ct;
            A.Cdu[(size_t)e * 128 + k] = cd;
            red[k] = ds[k] * A.uu_ob[k] + ds[128 + k] * A.ta_ob[k] + ds[256 + k] * A.du_ob[k];
        }
        __syncthreads();
        for (int off = 64; off; off >>= 1) {
            if (k < off) red[k] += red[k + off];
            __syncthreads();
        }
        if (k == 0) A.bcomb[e] = A.dim_b[e] + red[0];
    }
}

struct AttnArgs {
    const float* qd; const float* kbaseT; const float* vbase; const float* cit;
    const float* qta; const float* ktaT; const float* vta;
    const float* qdu; const float* kduT; const float* vdu;
    const float* uu_in_w;
    float* ouu; float* ota; float* odu;
};

#define SCP 260   // ta/du sc row pitch (divisible by 4, 16B-aligned rows)
#define SCPU 516  // uu sc row pitch

// 3072 blocks. XCD swizzle: xcd = bid&7 -> b = xcd>>1. t = half*384 + idx:
//   t<256: ta/du (2h x 8r, N=256); t>=256: uu (2h x 2r, N=512)
__global__ __launch_bounds__(256) void attn_kernel(AttnArgs A)
{
    __shared__ __align__(16) float smem[5472];   // 21.9 KB
    int bid = blockIdx.x, tid = threadIdx.x;
    int xcd = bid & 7, idx = bid >> 3;
    int b = xcd >> 1, half = xcd & 1;
    int t = half * 384 + idx;

    if (t < 256) {
        // ================= ta / du: 2 heads x 8 rows, N=256 =================
        int kind = t >> 7;
        int u = t & 127;
        int hg = u >> 5, lt = u & 31;
        int l0 = lt * 8, bl0 = b * 256 + l0;
        const float* q  = kind ? A.qdu  : A.qta;
        const float* kT = kind ? A.kduT : A.ktaT;
        const float* v  = kind ? A.vdu  : A.vta;
        float* o        = kind ? A.odu  : A.ota;
        float* qs    = smem;           // 256 [l][d]
        float* sc    = smem + 256;     // 16 rows x SCP
        float* vpart = smem + 4416;    // 1024
        float* den   = smem + 5440;    // 16
        {
            int l = tid >> 5, d = tid & 31;
            qs[l * 32 + d] = q[(size_t)(bl0 + l) * 128 + hg * 32 + d];
        }
        __syncthreads();
        {   // scores + fused exp; d in steps of 4, q via ds_read_b128
            int n = tid;
            const float* kp = kT + ((size_t)b * 128 + hg * 32) * 256 + n;
            float acc[8][2];
#pragma unroll
            for (int l = 0; l < 8; ++l) { acc[l][0] = 0.f; acc[l][1] = 0.f; }
#pragma unroll
            for (int d4 = 0; d4 < 8; ++d4) {
                float kv0 = kp[(size_t)(d4 * 4)     * 256];
                float kv1 = kp[(size_t)(d4 * 4 + 1) * 256];
                float kv2 = kp[(size_t)(d4 * 4 + 2) * 256];
                float kv3 = kp[(size_t)(d4 * 4 + 3) * 256];
                int hl = d4 >> 2;
#pragma unroll
                for (int l = 0; l < 8; ++l) {
                    float4 q4 = *(const float4*)(qs + l * 32 + d4 * 4);
                    acc[l][hl] += q4.x * kv0 + q4.y * kv1 + q4.z * kv2 + q4.w * kv3;
                }
            }
#pragma unroll
            for (int hl = 0; hl < 2; ++hl)
#pragma unroll
                for (int l = 0; l < 8; ++l)
                    sc[(hl * 8 + l) * SCP + n] = __expf(acc[l][hl] * 0.25f);
        }
        __syncthreads();
        {   // den: 16 groups x 16 lanes, strided float4 row sums
            int g = tid >> 4, j = tid & 15;
            const float4* row4 = (const float4*)(sc + g * SCP);
            float4 s4 = row4[j];
            float4 b1 = row4[j + 16], b2 = row4[j + 32], b3 = row4[j + 48];
            s4.x += b1.x + b2.x + b3.x; s4.y += b1.y + b2.y + b3.y;
            s4.z += b1.z + b2.z + b3.z; s4.w += b1.w + b2.w + b3.w;
            float s = s4.x + s4.y + s4.z + s4.w;
#pragma unroll
            for (int off = 8; off; off >>= 1) s += __shfl_down(s, off, 16);
            if (j == 0) den[g] = s;
        }
        __syncthreads();
        {   // V pass: p via float4 over n; coalesced float4 V rows
            int col4 = tid & 7, l = (tid >> 3) & 7, nh = tid >> 6;
            const float4* v4 = (const float4*)v + (size_t)b * 256 * 32 + hg * 8 + col4;
            const float4* p4 = (const float4*)(sc + ((col4 >> 2) * 8 + l) * SCP) + nh * 16;
            float4 a4 = { 0.f, 0.f, 0.f, 0.f };
            int n0 = nh * 64;
#pragma unroll 4
            for (int n4 = 0; n4 < 16; ++n4) {
                float4 pv = p4[n4];
                int n = n0 + n4 * 4;
                float4 vv0 = v4[(size_t)n * 32];
                float4 vv1 = v4[(size_t)(n + 1) * 32];
                float4 vv2 = v4[(size_t)(n + 2) * 32];
                float4 vv3 = v4[(size_t)(n + 3) * 32];
                a4.x += pv.x * vv0.x + pv.y * vv1.x + pv.z * vv2.x + pv.w * vv3.x;
                a4.y += pv.x * vv0.y + pv.y * vv1.y + pv.z * vv2.y + pv.w * vv3.y;
                a4.z += pv.x * vv0.z + pv.y * vv1.z + pv.z * vv2.z + pv.w * vv3.z;
                a4.w += pv.x * vv0.w + pv.y * vv1.w + pv.z * vv2.w + pv.w * vv3.w;
            }
            ((float4*)vpart)[nh * 64 + l * 8 + col4] = a4;
        }
        __syncthreads();
        {   // reduce 4 n-chunks + write
            int col = tid & 31, l = tid >> 5;
            int col4 = col >> 2, j = col & 3;
            int base = (l * 8 + col4) * 4 + j;
            float sum = vpart[base] + vpart[256 + base] + vpart[512 + base] + vpart[768 + base];
            o[(size_t)(bl0 + l) * 128 + hg * 32 + col] = sum / den[(col >> 4) * 8 + l];
        }
    } else {
        // ================= uu: 2 heads x 2 rows, N=512, rank-2 ci =================
        int u = t - 256;
        int hg = u >> 7, lt = u & 127;
        int l0 = lt * 2, bl0 = b * 256 + l0;
        float* qs    = smem;           // 64
        float* sc    = smem + 64;      // 4 rows x SCPU
        float* ci0s  = smem + 2128;    // 1024 [l][n]
        float* ci1s  = smem + 3152;    // 1024
        float* vpart = smem + 4176;    // 1024
        float* qkA   = smem + 5200;    // 4 [hl*2+l]
        float* qkB   = qkA + 4;
        float* den   = qkB + 4;
        float* hs0   = den + 4;
        float* hs1   = hs0 + 4;
        if (tid < 64) {
            int l = tid >> 5, d = tid & 31;
            qs[l * 32 + d] = A.qd[(size_t)(bl0 + l) * 128 + hg * 32 + d];
        }
        {
            ((float4*)ci0s)[tid] = ((const float4*)(A.cit + ((size_t)b * 512 + l0) * 512))[tid];
            ((float4*)ci1s)[tid] = ((const float4*)(A.cit + ((size_t)b * 512 + 256 + l0) * 512))[tid];
        }
        __syncthreads();
        if (tid < 4) {
            int hl = tid >> 1, l = tid & 1;
            float a = 0.f, c = 0.f;
#pragma unroll
            for (int d = 0; d < 16; ++d) {
                float qv = qs[l * 32 + hl * 16 + d];
                int wr = 128 + hg * 32 + hl * 16 + d;
                a += qv * A.uu_in_w[(size_t)wr * 128 + 126];
                c += qv * A.uu_in_w[(size_t)wr * 128 + 127];
            }
            qkA[tid] = a; qkB[tid] = c;
        }
        __syncthreads();
        {   // scores + fused exp; d in steps of 4, q via ds_read_b128
            const float* kp = A.kbaseT + ((size_t)b * 128 + hg * 32) * 512 + tid;
            float acc[2][2][2];    // [chunk][l][hl]
#pragma unroll
            for (int r = 0; r < 2; ++r)
#pragma unroll
                for (int l = 0; l < 2; ++l) { acc[r][l][0] = 0.f; acc[r][l][1] = 0.f; }
#pragma unroll
            for (int d4 = 0; d4 < 8; ++d4) {
                int hl = d4 >> 2;
                float kva[4], kvb[4];
#pragma unroll
                for (int j = 0; j < 4; ++j) {
                    kva[j] = kp[(size_t)(d4 * 4 + j) * 512];
                    kvb[j] = kp[(size_t)(d4 * 4 + j) * 512 + 256];
                }
#pragma unroll
                for (int l = 0; l < 2; ++l) {
                    float4 q4 = *(const float4*)(qs + l * 32 + d4 * 4);
                    acc[0][l][hl] += q4.x * kva[0] + q4.y * kva[1] + q4.z * kva[2] + q4.w * kva[3];
                    acc[1][l][hl] += q4.x * kvb[0] + q4.y * kvb[1] + q4.z * kvb[2] + q4.w * kvb[3];
                }
            }
#pragma unroll
            for (int r = 0; r < 2; ++r) {
                int n = tid + r * 256;
#pragma unroll
                for (int l = 0; l < 2; ++l) {
                    float c0 = ci0s[l * 512 + n], c1 = ci1s[l * 512 + n];
#pragma unroll
                    for (int hl = 0; hl < 2; ++hl) {
                        int g = hl * 2 + l;
                        sc[g * SCPU + n] =
                            __expf((acc[r][l][hl] + c0 * qkA[g] + c1 * qkB[g]) * 0.25f);
                    }
                }
            }
        }
        __syncthreads();
        {   // den + ci sums: 4 groups x 64 lanes, float4 reads
            int g = tid >> 6, j = tid & 63;
            int l = g & 1;
            const float4* row4 = (const float4*)(sc + g * SCPU);
            const float4* c04 = (const float4*)(ci0s + l * 512);
            const float4* c14 = (const float4*)(ci1s + l * 512);
            float s = 0.f, a0 = 0.f, a1 = 0.f;
#pragma unroll
            for (int k = 0; k < 2; ++k) {
                float4 pv = row4[j + k * 64];
                float4 cv0 = c04[j + k * 64];
                float4 cv1 = c14[j + k * 64];
                s  += pv.x + pv.y + pv.z + pv.w;
                a0 += pv.x * cv0.x + pv.y * cv0.y + pv.z * cv0.z + pv.w * cv0.w;
                a1 += pv.x * cv1.x + pv.y * cv1.y + pv.z * cv1.z + pv.w * cv1.w;
            }
#pragma unroll
            for (int off = 32; off; off >>= 1) {
                s  += __shfl_down(s, off, 64);
                a0 += __shfl_down(a0, off, 64);
                a1 += __shfl_down(a1, off, 64);
            }
            if (j == 0) { den[g] = s; hs0[g] = a0; hs1[g] = a1; }
        }
        __syncthreads();
        {   // V pass: p via float4 over n
            int col4 = tid & 7, l = (tid >> 3) & 1, nh = tid >> 4;
            const float4* v4 = (const float4*)A.vbase + (size_t)b * 512 * 32 + hg * 8 + col4;
            const float4* p4 = (const float4*)(sc + ((col4 >> 2) * 2 + l) * SCPU) + nh * 8;
            float4 a4 = { 0.f, 0.f, 0.f, 0.f };
            int n0 = nh * 32;
#pragma unroll 4
            for (int n4 = 0; n4 < 8; ++n4) {
                float4 pv = p4[n4];
                int n = n0 + n4 * 4;
                float4 vv0 = v4[(size_t)n * 32];
                float4 vv1 = v4[(size_t)(n + 1) * 32];
                float4 vv2 = v4[(size_t)(n + 2) * 32];
                float4 vv3 = v4[(size_t)(n + 3) * 32];
                a4.x += pv.x * vv0.x + pv.y * vv1.x + pv.z * vv2.x + pv.w * vv3.x;
                a4.y += pv.x * vv0.y + pv.y * vv1.y + pv.z * vv2.y + pv.w * vv3.y;
                a4.z += pv.x * vv0.z + pv.y * vv1.z + pv.z * vv2.z + pv.w * vv3.z;
                a4.w += pv.x * vv0.w + pv.y * vv1.w + pv.z * vv2.w + pv.w * vv3.w;
            }
            ((float4*)vpart)[nh * 16 + l * 8 + col4] = a4;
        }
        __syncthreads();
        if (tid < 64) {   // reduce 16 n-chunks + rank-2 V correction + write
            int col = tid & 31, l = tid >> 5;
            int colglob = hg * 32 + col;
            int g = (col >> 4) * 2 + l;
            int base = (l * 8 + (col >> 2)) * 4 + (col & 3);
            float sum = 0.f;
#pragma unroll
            for (int nh = 0; nh < 16; ++nh) sum += vpart[nh * 64 + base];
            float wv126 = A.uu_in_w[(size_t)(256 + colglob) * 128 + 126];
            float wv127 = A.uu_in_w[(size_t)(256 + colglob) * 128 + 127];
            A.ouu[(size_t)(bl0 + l) * 128 + colglob] =
                (sum + hs0[g] * wv126 + hs1[g] * wv127) / den[g];
        }
    }
}

// epilogue: 256 blocks x 4 rows
__global__ __launch_bounds__(256) void epilogue_kernel(
    const float* __restrict__ ouu, const float* __restrict__ ota,
    const float* __restrict__ odu,
    const float* __restrict__ Cuu, const float* __restrict__ Cta,
    const float* __restrict__ Cdu, const float* __restrict__ bcomb,
    float* __restrict__ y, float* __restrict__ gstat)
{
    __shared__ __align__(16) float xs[4 * 384];
    __shared__ float vp[512];
    int m0 = blockIdx.x * 4;
    int tid = threadIdx.x;
    for (int i = tid; i < 1536; i += 256) {
        int r = i / 384, c = i - r * 384;
        float v;
        if (c < 128)      v = ouu[(size_t)(m0 + r) * 128 + c];
        else if (c < 256) v = ota[(size_t)(m0 + r) * 128 + c - 128];
        else              v = odu[(size_t)(m0 + r) * 128 + c - 256];
        xs[i] = v;
    }
    __syncthreads();
    int e = tid & 127, half = tid >> 7;
    const float4* cu4 = (const float4*)(Cuu + (size_t)e * 128);
    const float4* ct4 = (const float4*)(Cta + (size_t)e * 128);
    const float4* cd4 = (const float4*)(Cdu + (size_t)e * 128);
    const float4* xs4 = (const float4*)xs;
    float bc = bcomb[e];
    float acc[2] = { bc, bc };
    int r0 = half * 2;
#pragma unroll 4
    for (int c = 0; c < 32; ++c) {
        float4 a = cu4[c], bb = ct4[c], d = cd4[c];
#pragma unroll
        for (int rr = 0; rr < 2; ++rr) {
            float4 xu = xs4[(r0 + rr) * 96 + c];
            float4 xt = xs4[(r0 + rr) * 96 + 32 + c];
            float4 xd = xs4[(r0 + rr) * 96 + 64 + c];
            acc[rr] += a.x * xu.x + a.y * xu.y + a.z * xu.z + a.w * xu.w
                     + bb.x * xt.x + bb.y * xt.y + bb.z * xt.z + bb.w * xt.w
                     + d.x * xd.x + d.y * xd.y + d.z * xd.z + d.w * xd.w;
        }
    }
#pragma unroll
    for (int rr = 0; rr < 2; ++rr)
        y[(size_t)(m0 + r0 + rr) * 128 + e] = acc[rr];
    vp[tid] = acc[0] + acc[1];
    vp[256 + tid] = acc[0] * acc[0] + acc[1] * acc[1];
    __syncthreads();
    if (tid < 128) {
        float* gs = gstat + (blockIdx.x & 15) * 256;
        atomicAdd(gs + tid, vp[tid] + vp[tid + 128]);
        atomicAdd(gs + 128 + tid, vp[256 + tid] + vp[256 + tid + 128]);
    }
}

__global__ __launch_bounds__(256) void bn_apply(
    const float* __restrict__ y, const float* __restrict__ gstat,
    const float* __restrict__ gamma, const float* __restrict__ beta,
    float* __restrict__ out)
{
    int gid = blockIdx.x * 256 + threadIdx.x;
    int c0 = (gid & 31) * 4;
    float4 v = ((const float4*)y)[gid];
    float r[4] = { v.x, v.y, v.z, v.w };
#pragma unroll
    for (int k = 0; k < 4; ++k) {
        int c = c0 + k;
        float s = 0.f, s2 = 0.f;
#pragma unroll
        for (int cp = 0; cp < 16; ++cp) {
            s  += gstat[cp * 256 + c];
            s2 += gstat[cp * 256 + 128 + c];
        }
        float mean = s * (1.f / 1024.f);
        float var = s2 * (1.f / 1024.f) - mean * mean;
        float inv = rsqrtf(var + 1e-5f);
        r[k] = fmaxf((r[k] - mean) * inv * gamma[c] + beta[c], 0.f);
    }
    float4 ov = { r[0], r[1], r[2], r[3] };
    ((float4*)out)[gid] = ov;
}

extern "C" void kernel_launch(void* const* d_in, const int* in_sizes, int n_in,
                              void* d_out, int out_size, void* d_ws, size_t ws_size,
                              hipStream_t stream)
{
    (void)in_sizes; (void)n_in; (void)out_size; (void)ws_size;
    const float* UUMat    = (const float*)d_in[0];
    const float* DUMat    = (const float*)d_in[1];
    const float* TAMat    = (const float*)d_in[2];
    const float* CIMat    = (const float*)d_in[3];
    const float* uu_in_w  = (const float*)d_in[4];
    const float* uu_in_b  = (const float*)d_in[5];
    const float* uu_out_w = (const float*)d_in[6];
    const float* uu_out_b = (const float*)d_in[7];
    const float* ta_in_w  = (const float*)d_in[8];
    const float* ta_in_b  = (const float*)d_in[9];
    const float* ta_out_w = (const float*)d_in[10];
    const float* ta_out_b = (const float*)d_in[11];
    const float* du_in_w  = (const float*)d_in[12];
    const float* du_in_b  = (const float*)d_in[13];
    const float* du_out_w = (const float*)d_in[14];
    const float* du_out_b = (const float*)d_in[15];
    const float* dim_w    = (const float*)d_in[16];
    const float* dim_b    = (const float*)d_in[17];
    const float* bn_g     = (const float*)d_in[18];
    const float* bn_b     = (const float*)d_in[19];

    const int BL = 1024, BN = 2048;
    float* ws = (float*)d_ws;
    float* gstat  = ws; ws += 16 * 256;
    float* cit    = ws; ws += (size_t)4 * 512 * 512;
    float* qd     = ws; ws += (size_t)BL * 128;
    float* kbaseT = ws; ws += (size_t)BN * 128;   // [b][128][512]
    float* vbase  = ws; ws += (size_t)BN * 128;
    float* qta    = ws; ws += (size_t)BL * 128;
    float* ktaT   = ws; ws += (size_t)BL * 128;   // [b][128][256]
    float* vta    = ws; ws += (size_t)BL * 128;
    float* qdu    = ws; ws += (size_t)BL * 128;
    float* kduT   = ws; ws += (size_t)BL * 128;   // [b][128][256]
    float* vdu    = ws; ws += (size_t)BL * 128;
    float* ouu    = ws; ws += (size_t)BL * 128;
    float* ota    = ws; ws += (size_t)BL * 128;
    float* odu    = ws; ws += (size_t)BL * 128;
    float* yy     = ws; ws += (size_t)BL * 128;
    float* Cuu    = ws; ws += 128 * 128;
    float* Cta    = ws; ws += 128 * 128;
    float* Cdu    = ws; ws += 128 * 128;
    float* bcomb  = ws; ws += 128;

    PreArgs P;
    P.x[0] = DUMat; P.W[0] = uu_in_w;             P.bia[0] = uu_in_b;       P.out[0] = qd;     P.Kdim[0] = 128; P.transNb[0] = 0;
    P.x[1] = DUMat; P.W[1] = ta_in_w;             P.bia[1] = ta_in_b;       P.out[1] = qta;    P.Kdim[1] = 128; P.transNb[1] = 0;
    P.x[2] = TAMat; P.W[2] = ta_in_w + 128 * 128; P.bia[2] = ta_in_b + 128; P.out[2] = ktaT;   P.Kdim[2] = 128; P.transNb[2] = 256;
    P.x[3] = TAMat; P.W[3] = ta_in_w + 256 * 128; P.bia[3] = ta_in_b + 256; P.out[3] = vta;    P.Kdim[3] = 128; P.transNb[3] = 0;
    P.x[4] = DUMat; P.W[4] = du_in_w;             P.bia[4] = du_in_b;       P.out[4] = qdu;    P.Kdim[4] = 128; P.transNb[4] = 0;
    P.x[5] = DUMat; P.W[5] = du_in_w + 128 * 128; P.bia[5] = du_in_b + 128; P.out[5] = kduT;   P.Kdim[5] = 128; P.transNb[5] = 256;
    P.x[6] = DUMat; P.W[6] = du_in_w + 256 * 128; P.bia[6] = du_in_b + 256; P.out[6] = vdu;    P.Kdim[6] = 128; P.transNb[6] = 0;
    P.x[7] = UUMat; P.W[7] = uu_in_w + 128 * 128; P.bia[7] = uu_in_b + 128; P.out[7] = kbaseT; P.Kdim[7] = 126; P.transNb[7] = 512;
    P.x[8] = UUMat; P.W[8] = uu_in_w + 256 * 128; P.bia[8] = uu_in_b + 256; P.out[8] = vbase;  P.Kdim[8] = 126; P.transNb[8] = 0;
    P.CIMat = CIMat; P.cit = cit;
    P.dim_w = dim_w; P.dim_b = dim_b;
    P.uu_ow = uu_out_w; P.uu_ob = uu_out_b;
    P.ta_ow = ta_out_w; P.ta_ob = ta_out_b;
    P.du_ow = du_out_w; P.du_ob = du_out_b;
    P.Cuu = Cuu; P.Cta = Cta; P.Cdu = Cdu; P.bcomb = bcomb;
    P.gstat = gstat;

    AttnArgs T;
    T.qd = qd; T.kbaseT = kbaseT; T.vbase = vbase; T.cit = cit;
    T.qta = qta; T.ktaT = ktaT; T.vta = vta;
    T.qdu = qdu; T.kduT = kduT; T.vdu = vdu;
    T.uu_in_w = uu_in_w;
    T.ouu = ouu; T.ota = ota; T.odu = odu;

    hipLaunchKernelGGL(pre_fused, dim3(1856), dim3(256), 0, stream, P);
    hipLaunchKernelGGL(attn_kernel, dim3(3072), dim3(256), 0, stream, T);
    hipLaunchKernelGGL(epilogue_kernel, dim3(256), dim3(256), 0, stream,
                       ouu, ota, odu, Cuu, Cta, Cdu, bcomb, yy, gstat);
    hipLaunchKernelGGL(bn_apply, dim3(128), dim3(256), 0, stream,
                       yy, gstat, bn_g, bn_b, (float*)d_out);
}